// Round 9
// baseline (4329.019 us; speedup 1.0000x reference)
//
#include <hip/hip_runtime.h>
#include <hip/hip_fp16.h>
#include <cstddef>

// FDRNN: fuzzy -> FC(200->1024->1024->1024->128) -> 2-layer tanh RNN (H=512)
// B=64, S=512 -> 32768 rows.
//
// R10: R7/R8/R9 all proved the compiler clamps 512-thread blocks to ~128
// VGPR/wave (three knob spellings, identical 776-784us, VGPR 124-128) ->
// ~194KB/step of W streams via scratch/L2 at ~60B/cyc = the whole 3660
// cyc/step. R10 changes the SHAPE: 256-thread blocks, __launch_bounds__(256,1)
// -> 1 wave/EU -> 512-VGPR budget (m24: 450 no-spill exists). Thread owns 2
// output rows; W fully resident: 96 named+pinned f32x4 (384 VGPR) + 16
// j-groups/row in XOR-swizzled LDS (128 KB). No psum, no cross-thread
// reduce, ONE barrier/step. Model ~1800-2200 cyc/step (from 3660).

typedef _Float16 half8 __attribute__((ext_vector_type(8)));
typedef float f32x4 __attribute__((ext_vector_type(4)));
typedef float f32v4 __attribute__((ext_vector_type(4)));
typedef _Float16 v2h __attribute__((ext_vector_type(2)));

__device__ __forceinline__ void gld_lds16(const void* g, void* lds) {
  __builtin_amdgcn_global_load_lds(
      (const __attribute__((address_space(1))) unsigned int*)g,
      (__attribute__((address_space(3))) unsigned int*)lds, 16, 0, 0);
}

// ---------------- fuzzy (fp16 out, K padded 200->256) ----------------
__global__ void fuzzy16(const float* __restrict__ x, const float* __restrict__ fp,
                        _Float16* __restrict__ z, int nrows) {
  int idx = blockIdx.x * blockDim.x + threadIdx.x;
  if (idx >= nrows * 256) return;
  int r = idx >> 8;
  int f = idx & 255;
  float v = 0.f;
  if (f < 200) {
    int i = f % 50;
    float xv = x[r * 50 + i];
    float mu = fp[2 * f];
    float sg = fp[2 * f + 1];
    float d = xv - mu;
    v = expf(-(d * d) / sg);
  }
  z[idx] = (_Float16)v;
}

// ---------------- weight fp32 -> fp16 (with optional K zero-pad) -------------
__global__ void cvt_w16(const float* __restrict__ W, _Float16* __restrict__ O,
                        int rows, int kin, int kpad) {
  int idx = blockIdx.x * blockDim.x + threadIdx.x;
  if (idx >= rows * kpad) return;
  int r = idx / kpad;
  int k = idx - r * kpad;
  O[idx] = (k < kin) ? (_Float16)W[(size_t)r * kin + k] : (_Float16)0.f;
}

// ---------------- MFMA fp16 GEMM: C16[M][N] = A16[M][K] @ W16[N][K]^T + b ----
__global__ __launch_bounds__(256) void gemm16(
    const _Float16* __restrict__ A, const _Float16* __restrict__ W,
    const float* __restrict__ b1, const float* __restrict__ b2,
    _Float16* __restrict__ C, int M, int N, int K) {
  __shared__ _Float16 As[128 * 32];
  __shared__ _Float16 Bs[128 * 32];
  const int tid = threadIdx.x;
  const int bm = blockIdx.y * 128;
  const int bn = blockIdx.x * 128;
  const int lane = tid & 63;
  const int wv = tid >> 6;
  const int wm = (wv >> 1) * 64;
  const int wn = (wv & 1) * 64;
  const int frow = lane & 15;
  const int fk = (lane >> 4) * 8;

  const int srow = tid >> 2;
  const int scol = (tid & 3) * 16;  // bytes
  const char* gA = (const char*)(A + (size_t)(bm + srow) * K) + scol;
  const char* gB = (const char*)(W + (size_t)(bn + srow) * K) + scol;
  const size_t rowstep = (size_t)64 * K * 2;
  char* lA = (char*)As + tid * 16;
  char* lB = (char*)Bs + tid * 16;

  f32x4 acc[4][4] = {};

  for (int k0 = 0; k0 < K; k0 += 32) {
    gld_lds16(gA, lA);
    gld_lds16(gA + rowstep, lA + 4096);
    gld_lds16(gB, lB);
    gld_lds16(gB + rowstep, lB + 4096);
    gA += 64;
    gB += 64;
    __syncthreads();
    half8 af[4], bf[4];
#pragma unroll
    for (int i = 0; i < 4; i++) {
      af[i] = *(const half8*)(As + (wm + i * 16 + frow) * 32 + fk);
      bf[i] = *(const half8*)(Bs + (wn + i * 16 + frow) * 32 + fk);
    }
#pragma unroll
    for (int i = 0; i < 4; i++)
#pragma unroll
      for (int j = 0; j < 4; j++)
        acc[i][j] = __builtin_amdgcn_mfma_f32_16x16x32_f16(af[i], bf[j], acc[i][j], 0, 0, 0);
    __syncthreads();
  }

  float bias[4];
#pragma unroll
  for (int j = 0; j < 4; j++) {
    int col = bn + wn + j * 16 + frow;
    bias[j] = b1[col] + (b2 ? b2[col] : 0.f);
  }
  const int r0 = (lane >> 4) * 4;
#pragma unroll
  for (int i = 0; i < 4; i++) {
#pragma unroll
    for (int r = 0; r < 4; r++) {
      int row = bm + wm + i * 16 + r0 + r;
      _Float16* Cp = C + (size_t)row * N + bn + wn + frow;
#pragma unroll
      for (int j = 0; j < 4; j++)
        Cp[j * 16] = (_Float16)(acc[i][j][r] + bias[j]);
    }
  }
}

// ---------------- RNN weight pack (fp32 -> fp16, 16B groups) ----------------
// QW[j4*512 + o] = 8 fp16 = w_hh[o][8*j4 .. 8*j4+7]
__global__ void pack_whh_fp16(const float* __restrict__ W, float4* __restrict__ QW) {
  int idx = blockIdx.x * blockDim.x + threadIdx.x;
  if (idx >= 32768) return;
  int j4 = idx >> 9;
  int o = idx & 511;
  const float* src = W + (size_t)o * 512 + j4 * 8;
  __align__(16) __half2 p[4];
#pragma unroll
  for (int k = 0; k < 4; k++)
    p[k] = __halves2half2(__float2half(src[2 * k]), __float2half(src[2 * k + 1]));
  QW[idx] = *(const float4*)p;
}

__device__ __forceinline__ float dot2acc(float wbits, float hbits, float acc) {
#if __has_builtin(__builtin_amdgcn_fdot2)
  return __builtin_amdgcn_fdot2(__builtin_bit_cast(v2h, wbits),
                                __builtin_bit_cast(v2h, hbits), acc, false);
#else
  float2 wf = __half22float2(__builtin_bit_cast(__half2, wbits));
  float2 hf = __half22float2(__builtin_bit_cast(__half2, hbits));
  return fmaf(wf.x, hf.x, fmaf(wf.y, hf.y, acc));
#endif
}

#define FORG48(X) \
  X(0) X(1) X(2) X(3) X(4) X(5) X(6) X(7) \
  X(8) X(9) X(10) X(11) X(12) X(13) X(14) X(15) \
  X(16) X(17) X(18) X(19) X(20) X(21) X(22) X(23) \
  X(24) X(25) X(26) X(27) X(28) X(29) X(30) X(31) \
  X(32) X(33) X(34) X(35) X(36) X(37) X(38) X(39) \
  X(40) X(41) X(42) X(43) X(44) X(45) X(46) X(47)

// 96 named f32x4 (rows A and B, j-groups 0..47) = 384 VGPRs, pinned so the
// loads cannot be rematerialized (asm output is opaque to remat).
#define DECLW(g)                                                        \
  f32x4 wa##g = qA[(g) << 9]; asm volatile("" : "+v"(wa##g));           \
  f32x4 wb##g = qB[(g) << 9]; asm volatile("" : "+v"(wb##g));

#define DOTRG(g)                                       \
  {                                                    \
    f32v4 hq = hs4[g];                                 \
    aA0 = dot2acc(wa##g.x, hq.x, aA0);                 \
    aA1 = dot2acc(wa##g.y, hq.y, aA1);                 \
    aA2 = dot2acc(wa##g.z, hq.z, aA2);                 \
    aA3 = dot2acc(wa##g.w, hq.w, aA3);                 \
    aB0 = dot2acc(wb##g.x, hq.x, aB0);                 \
    aB1 = dot2acc(wb##g.y, hq.y, aB1);                 \
    aB2 = dot2acc(wb##g.z, hq.z, aB2);                 \
    aB3 = dot2acc(wb##g.w, hq.w, aB3);                 \
  }

// ---------------- RNN: 256-thr block per batch, W FULLY resident -------------
// Thread t owns output rows o0=t, o1=t+256 (full j range each -> no psum, no
// cross-thread reduce, ONE barrier/step). W: j-groups 0..47 in 96 pinned
// f32x4 (384 VGPR); groups 48..63 in LDS wlds[512][16] (128 KB), slot
// XOR-swizzled by (row&15) to break the 256B-stride bank conflict.
__global__ __launch_bounds__(256, 1) void rnn_full_k(
    const _Float16* __restrict__ pre,  // [512][512] per batch, biases folded
    const f32v4* __restrict__ QW,      // packed fp16 w_hh [64 grp][512 o]
    float* __restrict__ out32,         // nullable: final fp32 output
    _Float16* __restrict__ out16) {    // nullable: fp16 h for next-layer GEMM
  const int b = blockIdx.x;
  const int o0 = threadIdx.x;
  const int o1 = o0 + 256;

  __shared__ f32v4 wlds[512][16];                // 128 KB, swizzled slots
  __shared__ __align__(16) __half hbuf[2][512];  // 2 KB double-buffered h

  const f32v4* qA = QW + o0;
  const f32v4* qB = QW + o1;
  FORG48(DECLW)

  const int sw = o0 & 15;  // == o1 & 15
#pragma unroll
  for (int gi = 0; gi < 16; gi++) {
    wlds[o0][gi ^ sw] = qA[(48 + gi) << 9];
    wlds[o1][gi ^ sw] = qB[(48 + gi) << 9];
  }
  hbuf[0][o0] = __float2half(0.f);
  hbuf[0][o1] = __float2half(0.f);
  __syncthreads();

  const _Float16* preb = pre + (size_t)b * 262144;
  float* ob32 = out32 ? out32 + (size_t)b * 262144 : nullptr;
  _Float16* ob16 = out16 ? out16 + (size_t)b * 262144 : nullptr;

  _Float16 pA = preb[o0], pB = preb[o1];
  int p = 0;
  for (int t = 0; t < 512; t++) {
    const f32v4* hs4 = (const f32v4*)hbuf[p];
    float aA0 = (float)pA, aA1 = 0.f, aA2 = 0.f, aA3 = 0.f;
    float aB0 = (float)pB, aB1 = 0.f, aB2 = 0.f, aB3 = 0.f;
    FORG48(DOTRG)
#pragma unroll
    for (int gi = 0; gi < 16; gi++) {
      f32v4 hq = hs4[48 + gi];
      f32v4 qa = wlds[o0][gi ^ sw];
      f32v4 qb = wlds[o1][gi ^ sw];
      aA0 = dot2acc(qa.x, hq.x, aA0);
      aA1 = dot2acc(qa.y, hq.y, aA1);
      aA2 = dot2acc(qa.z, hq.z, aA2);
      aA3 = dot2acc(qa.w, hq.w, aA3);
      aB0 = dot2acc(qb.x, hq.x, aB0);
      aB1 = dot2acc(qb.y, hq.y, aB1);
      aB2 = dot2acc(qb.z, hq.z, aB2);
      aB3 = dot2acc(qb.w, hq.w, aB3);
    }
    if (t < 511) {  // prefetch next pre
      pA = preb[(t + 1) * 512 + o0];
      pB = preb[(t + 1) * 512 + o1];
    }
    float vA = (aA0 + aA1) + (aA2 + aA3);
    float vB = (aB0 + aB1) + (aB2 + aB3);
    // fast tanh: 1 - 2/(exp(2v)+1)
    float zA = __expf(2.f * vA);
    float hA = fmaf(-2.f, __builtin_amdgcn_rcpf(zA + 1.f), 1.f);
    float zB = __expf(2.f * vB);
    float hB = fmaf(-2.f, __builtin_amdgcn_rcpf(zB + 1.f), 1.f);
    hbuf[p ^ 1][o0] = __float2half(hA);
    hbuf[p ^ 1][o1] = __float2half(hB);
    if (ob32) {
      ob32[t * 512 + o0] = hA;
      ob32[t * 512 + o1] = hB;
    }
    if (ob16) {
      ob16[t * 512 + o0] = (_Float16)hA;
      ob16[t * 512 + o1] = (_Float16)hB;
    }
    p ^= 1;
    __syncthreads();  // h_t fully written before next step's reads
  }
}

extern "C" void kernel_launch(void* const* d_in, const int* in_sizes, int n_in,
                              void* d_out, int out_size, void* d_ws, size_t ws_size,
                              hipStream_t stream) {
  const float* x     = (const float*)d_in[0];
  const float* fp    = (const float*)d_in[1];
  const float* fc0_w = (const float*)d_in[2];
  const float* fc0_b = (const float*)d_in[3];
  const float* fc1_w = (const float*)d_in[4];
  const float* fc1_b = (const float*)d_in[5];
  const float* fc2_w = (const float*)d_in[6];
  const float* fc2_b = (const float*)d_in[7];
  const float* fc3_w = (const float*)d_in[8];
  const float* fc3_b = (const float*)d_in[9];
  const float* w_ih0 = (const float*)d_in[10];
  const float* w_hh0 = (const float*)d_in[11];
  const float* b_ih0 = (const float*)d_in[12];
  const float* b_hh0 = (const float*)d_in[13];
  const float* w_ih1 = (const float*)d_in[14];
  const float* w_hh1 = (const float*)d_in[15];
  const float* b_ih1 = (const float*)d_in[16];
  const float* b_hh1 = (const float*)d_in[17];
  float* out = (float*)d_out;
  float* ws  = (float*)d_ws;

  // ws layout (float offsets). Total ~73.8 MB.
  _Float16* preH = (_Float16*)ws;                    // [32768][512] fp16
  float* U = ws + 8388608;
  _Float16* h16 = (_Float16*)U;                      // RNN phase: [32768][512]
  _Float16* t0  = (_Float16*)U;                      // FC phase: [8192][1024]
  float* R2 = U + 4194304;
  _Float16* t1  = (_Float16*)R2;                     // [8192][1024]
  _Float16* zc  = (_Float16*)R2;                     // [8192][256]
  _Float16* f3  = (_Float16*)(R2 + 1048576);         // [8192][128]
  float* wbase = ws + 16777216;
  float4*   QW0   = (float4*)wbase;
  float4*   QW1   = (float4*)(wbase + 131072);
  _Float16* fc0h  = (_Float16*)(wbase + 262144);
  _Float16* fc1h  = (_Float16*)(wbase + 393216);
  _Float16* fc2h  = (_Float16*)(wbase + 917504);
  _Float16* fc3h  = (_Float16*)(wbase + 1441792);
  _Float16* wih0h = (_Float16*)(wbase + 1507328);
  _Float16* wih1h = (_Float16*)(wbase + 1540096);

  pack_whh_fp16<<<128, 256, 0, stream>>>(w_hh0, QW0);
  pack_whh_fp16<<<128, 256, 0, stream>>>(w_hh1, QW1);
  cvt_w16<<<1024, 256, 0, stream>>>(fc0_w, fc0h, 1024, 200, 256);
  cvt_w16<<<4096, 256, 0, stream>>>(fc1_w, fc1h, 1024, 1024, 1024);
  cvt_w16<<<4096, 256, 0, stream>>>(fc2_w, fc2h, 1024, 1024, 1024);
  cvt_w16<<<512, 256, 0, stream>>>(fc3_w, fc3h, 128, 1024, 1024);
  cvt_w16<<<256, 256, 0, stream>>>(w_ih0, wih0h, 512, 128, 128);
  cvt_w16<<<1024, 256, 0, stream>>>(w_ih1, wih1h, 512, 512, 512);

  const int CH = 8192;  // 32768 rows in 4 chunks
  for (int c = 0; c < 4; c++) {
    size_t row0 = (size_t)c * CH;
    fuzzy16<<<CH, 256, 0, stream>>>(x + row0 * 50, fp, zc, CH);
    gemm16<<<dim3(8, 64), 256, 0, stream>>>(zc, fc0h, fc0_b, nullptr, t0, CH, 1024, 256);
    gemm16<<<dim3(8, 64), 256, 0, stream>>>(t0, fc1h, fc1_b, nullptr, t1, CH, 1024, 1024);
    gemm16<<<dim3(8, 64), 256, 0, stream>>>(t1, fc2h, fc2_b, nullptr, t0, CH, 1024, 1024);
    gemm16<<<dim3(1, 64), 256, 0, stream>>>(t0, fc3h, fc3_b, nullptr, f3, CH, 128, 1024);
    gemm16<<<dim3(4, 64), 256, 0, stream>>>(f3, wih0h, b_ih0, b_hh0,
                                            preH + row0 * 512, CH, 512, 128);
  }

  // RNN layer 0: preH -> h16 (fp16, feeds layer-1 input projection)
  rnn_full_k<<<64, 256, 0, stream>>>(preH, (const f32v4*)QW0, nullptr, h16);
  // pre1 = h0 @ w_ih1^T + b_ih1 + b_hh1 (fp16 out into preH)
  gemm16<<<dim3(4, 256), 256, 0, stream>>>(h16, wih1h, b_ih1, b_hh1, preH, 32768, 512, 512);
  // RNN layer 1: preH -> final fp32 output
  rnn_full_k<<<64, 256, 0, stream>>>(preH, (const f32v4*)QW1, out, nullptr);
}

// Round 10
// 3571.491 us; speedup vs baseline: 1.2121x; 1.2121x over previous
//
#include <hip/hip_runtime.h>
#include <hip/hip_fp16.h>
#include <cstddef>

// FDRNN: fuzzy -> FC(200->1024->1024->1024->128) -> 2-layer tanh RNN (H=512)
// B=64, S=512 -> 32768 rows.
//
// R11: R7-R10 established: per-CU resident W caps at ~320KB of 512KB; the
// rest streams at ~60B/cyc = 3660 cyc/step, and DS alone floors a full
// single-CU matvec at ~2900 cyc. Structural change: 3-stage producer->
// consumer pipeline, 192 blocks = 64 batches x {A: w_hh0 recurrence,
// B: w_ih1 matvec, C: w_hh1 recurrence+tanh}. One-directional dataflow,
// 1-step lag, monotonic flags (R6-verified atomics), sc1 L3 data path,
// watermark prefetch. Each stage = R9's 5/2/1 matvec core (3660 cyc/step).
// RNN total ~= 512 x slowest-stage ~= 850us, replacing 776+55+776us.

typedef _Float16 half8 __attribute__((ext_vector_type(8)));
typedef float f32x4 __attribute__((ext_vector_type(4)));
typedef float f32v4 __attribute__((ext_vector_type(4)));
typedef _Float16 v2h __attribute__((ext_vector_type(2)));

__device__ __forceinline__ void gld_lds16(const void* g, void* lds) {
  __builtin_amdgcn_global_load_lds(
      (const __attribute__((address_space(1))) unsigned int*)g,
      (__attribute__((address_space(3))) unsigned int*)lds, 16, 0, 0);
}

// ---------------- fuzzy (fp16 out, K padded 200->256) ----------------
__global__ void fuzzy16(const float* __restrict__ x, const float* __restrict__ fp,
                        _Float16* __restrict__ z, int nrows) {
  int idx = blockIdx.x * blockDim.x + threadIdx.x;
  if (idx >= nrows * 256) return;
  int r = idx >> 8;
  int f = idx & 255;
  float v = 0.f;
  if (f < 200) {
    int i = f % 50;
    float xv = x[r * 50 + i];
    float mu = fp[2 * f];
    float sg = fp[2 * f + 1];
    float d = xv - mu;
    v = expf(-(d * d) / sg);
  }
  z[idx] = (_Float16)v;
}

// ---------------- weight fp32 -> fp16 (with optional K zero-pad) -------------
__global__ void cvt_w16(const float* __restrict__ W, _Float16* __restrict__ O,
                        int rows, int kin, int kpad) {
  int idx = blockIdx.x * blockDim.x + threadIdx.x;
  if (idx >= rows * kpad) return;
  int r = idx / kpad;
  int k = idx - r * kpad;
  O[idx] = (k < kin) ? (_Float16)W[(size_t)r * kin + k] : (_Float16)0.f;
}

// ---------------- MFMA fp16 GEMM: C16[M][N] = A16[M][K] @ W16[N][K]^T + b ----
__global__ __launch_bounds__(256) void gemm16(
    const _Float16* __restrict__ A, const _Float16* __restrict__ W,
    const float* __restrict__ b1, const float* __restrict__ b2,
    _Float16* __restrict__ C, int M, int N, int K) {
  __shared__ _Float16 As[128 * 32];
  __shared__ _Float16 Bs[128 * 32];
  const int tid = threadIdx.x;
  const int bm = blockIdx.y * 128;
  const int bn = blockIdx.x * 128;
  const int lane = tid & 63;
  const int wv = tid >> 6;
  const int wm = (wv >> 1) * 64;
  const int wn = (wv & 1) * 64;
  const int frow = lane & 15;
  const int fk = (lane >> 4) * 8;

  const int srow = tid >> 2;
  const int scol = (tid & 3) * 16;  // bytes
  const char* gA = (const char*)(A + (size_t)(bm + srow) * K) + scol;
  const char* gB = (const char*)(W + (size_t)(bn + srow) * K) + scol;
  const size_t rowstep = (size_t)64 * K * 2;
  char* lA = (char*)As + tid * 16;
  char* lB = (char*)Bs + tid * 16;

  f32x4 acc[4][4] = {};

  for (int k0 = 0; k0 < K; k0 += 32) {
    gld_lds16(gA, lA);
    gld_lds16(gA + rowstep, lA + 4096);
    gld_lds16(gB, lB);
    gld_lds16(gB + rowstep, lB + 4096);
    gA += 64;
    gB += 64;
    __syncthreads();
    half8 af[4], bf[4];
#pragma unroll
    for (int i = 0; i < 4; i++) {
      af[i] = *(const half8*)(As + (wm + i * 16 + frow) * 32 + fk);
      bf[i] = *(const half8*)(Bs + (wn + i * 16 + frow) * 32 + fk);
    }
#pragma unroll
    for (int i = 0; i < 4; i++)
#pragma unroll
      for (int j = 0; j < 4; j++)
        acc[i][j] = __builtin_amdgcn_mfma_f32_16x16x32_f16(af[i], bf[j], acc[i][j], 0, 0, 0);
    __syncthreads();
  }

  float bias[4];
#pragma unroll
  for (int j = 0; j < 4; j++) {
    int col = bn + wn + j * 16 + frow;
    bias[j] = b1[col] + (b2 ? b2[col] : 0.f);
  }
  const int r0 = (lane >> 4) * 4;
#pragma unroll
  for (int i = 0; i < 4; i++) {
#pragma unroll
    for (int r = 0; r < 4; r++) {
      int row = bm + wm + i * 16 + r0 + r;
      _Float16* Cp = C + (size_t)row * N + bn + wn + frow;
#pragma unroll
      for (int j = 0; j < 4; j++)
        Cp[j * 16] = (_Float16)(acc[i][j][r] + bias[j]);
    }
  }
}

// ---------------- RNN weight pack (fp32 -> fp16, 16B groups) ----------------
// QW[j4*512 + o] = 8 fp16 = w[o][8*j4 .. 8*j4+7]
__global__ void pack_whh_fp16(const float* __restrict__ W, float4* __restrict__ QW) {
  int idx = blockIdx.x * blockDim.x + threadIdx.x;
  if (idx >= 32768) return;
  int j4 = idx >> 9;
  int o = idx & 511;
  const float* src = W + (size_t)o * 512 + j4 * 8;
  __align__(16) __half2 p[4];
#pragma unroll
  for (int k = 0; k < 4; k++)
    p[k] = __halves2half2(__float2half(src[2 * k]), __float2half(src[2 * k + 1]));
  QW[idx] = *(const float4*)p;
}

__device__ __forceinline__ float dot2acc(float wbits, float hbits, float acc) {
#if __has_builtin(__builtin_amdgcn_fdot2)
  return __builtin_amdgcn_fdot2(__builtin_bit_cast(v2h, wbits),
                                __builtin_bit_cast(v2h, hbits), acc, false);
#else
  float2 wf = __half22float2(__builtin_bit_cast(__half2, wbits));
  float2 hf = __half22float2(__builtin_bit_cast(__half2, hbits));
  return fmaf(wf.x, hf.x, fmaf(wf.y, hf.y, acc));
#endif
}

__device__ __forceinline__ unsigned int spin_until(unsigned int* f, unsigned int need) {
  unsigned int v = __hip_atomic_load(f, __ATOMIC_RELAXED, __HIP_MEMORY_SCOPE_AGENT);
  while (v < need) {
    __builtin_amdgcn_s_sleep(8);
    v = __hip_atomic_load(f, __ATOMIC_RELAXED, __HIP_MEMORY_SCOPE_AGENT);
  }
  return v;
}

// R9 matvec core: per thread 8 o-rows (o=l+64k) x 8 j-groups; 5 groups pinned
// VGPR (160), 2 in LDS (128KB), 1 streamed from L2 (issued early).
#define DECLK(k)                                                           \
  f32x4 w##k##_0 = qb[(0 << 9) + ((k) << 6)]; asm volatile("" : "+v"(w##k##_0)); \
  f32x4 w##k##_1 = qb[(1 << 9) + ((k) << 6)]; asm volatile("" : "+v"(w##k##_1)); \
  f32x4 w##k##_2 = qb[(2 << 9) + ((k) << 6)]; asm volatile("" : "+v"(w##k##_2)); \
  f32x4 w##k##_3 = qb[(3 << 9) + ((k) << 6)]; asm volatile("" : "+v"(w##k##_3)); \
  f32x4 w##k##_4 = qb[(4 << 9) + ((k) << 6)]; asm volatile("" : "+v"(w##k##_4));

#define DOT1(k, g)                                  \
  acc##k = dot2acc(w##k##_##g.x, hq.x, acc##k);     \
  acc##k = dot2acc(w##k##_##g.y, hq.y, acc##k);     \
  acc##k = dot2acc(w##k##_##g.z, hq.z, acc##k);     \
  acc##k = dot2acc(w##k##_##g.w, hq.w, acc##k);

#define DOTG(g)                         \
  {                                     \
    f32v4 hq = hs4[w8 + (g)];           \
    DOT1(0, g) DOT1(1, g) DOT1(2, g)    \
    DOT1(3, g) DOT1(4, g) DOT1(5, g)    \
    DOT1(6, g) DOT1(7, g)               \
  }

#define DOTLK(gp, k)                                \
  {                                                 \
    f32v4 q = wl[((gp) << 9) + ((k) << 6)];         \
    acc##k = dot2acc(q.x, hq.x, acc##k);            \
    acc##k = dot2acc(q.y, hq.y, acc##k);            \
    acc##k = dot2acc(q.z, hq.z, acc##k);            \
    acc##k = dot2acc(q.w, hq.w, acc##k);            \
  }

#define DOTL(gp)                                    \
  {                                                 \
    f32v4 hq = hs4[w8 + 5 + (gp)];                  \
    DOTLK(gp, 0) DOTLK(gp, 1) DOTLK(gp, 2)          \
    DOTLK(gp, 3) DOTLK(gp, 4) DOTLK(gp, 5)          \
    DOTLK(gp, 6) DOTLK(gp, 7)                       \
  }

#define DOTS(k)                                     \
  acc##k = dot2acc(s##k.x, hq.x, acc##k);           \
  acc##k = dot2acc(s##k.y, hq.y, acc##k);           \
  acc##k = dot2acc(s##k.z, hq.z, acc##k);           \
  acc##k = dot2acc(s##k.w, hq.w, acc##k);

#define RING_MASK 63  // inbox1 ring depth 64 steps (B leads C by ~1)

// ---------------- 3-stage pipelined RNN ----------------
// grid 192: bid>>6 = stage (0=A w_hh0, 1=B w_ih1, 2=C w_hh1), b = bid&63.
// A: x = local h0 recurrence; pre-term preH; tanh; publish h0_t -> inbox0+flag0.
// B: x = inbox0[t] (flag0-gated); pre-term bias; publish pre1_t -> inbox1+flag1.
// C: x = local h1 recurrence; pre-term inbox1[t] (flag1-gated); tanh; out fp32.
// All cross-CU traffic: agent-scope (sc1, L3) atomics; monotonic flags with
// release; consumers use watermark prefetch so latency hides under the dots.
__global__ __attribute__((amdgpu_flat_work_group_size(512, 512),
                          amdgpu_waves_per_eu(2, 2)))
void rnn_pipe3_k(
    const _Float16* __restrict__ pre0,  // [64][512][512] stage-A pre (biases folded)
    const f32v4* __restrict__ QWA,      // packed w_hh0
    const f32v4* __restrict__ QWB,      // packed w_ih1
    const f32v4* __restrict__ QWC,      // packed w_hh1
    const float* __restrict__ bih1, const float* __restrict__ bhh1,
    _Float16* __restrict__ inbox0,      // [64][512][512] h0 (A->B)
    _Float16* __restrict__ inbox1,      // [64][64][512] pre1 ring (B->C)
    float* __restrict__ out32,          // [64][512][512] final
    unsigned int* __restrict__ flags) { // [0..63]=flag0, [64..127]=flag1
  const int bid = blockIdx.x;
  const int stage = bid >> 6;
  const int b = bid & 63;
  const int tid = threadIdx.x;
  const int w = tid >> 6;
  const int l = tid & 63;
  const int w8 = w << 3;

  __shared__ f32v4 wlds[16][512];                // 128 KB
  __shared__ float psum[8][512];                 // 16 KB
  __shared__ __align__(16) __half hbuf[2][512];  // 2 KB

  const f32v4* QW = (stage == 0) ? QWA : (stage == 1) ? QWB : QWC;
  const f32v4* qb = QW + ((size_t)(w8) << 9) + l;
  DECLK(0) DECLK(1) DECLK(2) DECLK(3) DECLK(4) DECLK(5) DECLK(6) DECLK(7)

  f32v4* wl = &wlds[w << 1][l];
#pragma unroll
  for (int gp = 0; gp < 2; gp++)
#pragma unroll
    for (int k = 0; k < 8; k++)
      wl[(gp << 9) + (k << 6)] = qb[((5 + gp) << 9) + (k << 6)];
  const f32v4* q7 = qb + (7 << 9);

  unsigned int* inflag  = (stage == 1) ? (flags + b) : (flags + 64 + b);
  unsigned int* outflag = (stage == 0) ? (flags + b) : (flags + 64 + b);
  unsigned long long* in0b = (unsigned long long*)(inbox0 + ((size_t)b << 18));
  unsigned int* out0b = (unsigned int*)(inbox0 + ((size_t)b << 18));
  unsigned int* io1b = (unsigned int*)(inbox1 + ((size_t)b << 15));  // 64*512 halfs
  const _Float16* preb = pre0 + ((size_t)b << 18);
  float* ob32 = out32 + ((size_t)b << 18);

  unsigned int fw = 0;
  float bias = 0.f;
  _Float16 pcur = (_Float16)0.f;
  unsigned long long xv = 0;

  if (stage == 0) {
    pcur = preb[tid];
    hbuf[0][tid] = __float2half(0.f);
  } else if (stage == 1) {
    bias = bih1[tid] + bhh1[tid];
    fw = spin_until(inflag, 1u);
    asm volatile("" ::: "memory");
    if (tid < 128) {
      unsigned long long v = __hip_atomic_load(in0b + tid, __ATOMIC_RELAXED,
                                               __HIP_MEMORY_SCOPE_AGENT);
      ((unsigned long long*)hbuf[0])[tid] = v;
    }
  } else {
    hbuf[0][tid] = __float2half(0.f);
    fw = spin_until(inflag, 1u);
    asm volatile("" ::: "memory");
    unsigned int pv = __hip_atomic_load(io1b + (tid >> 1), __ATOMIC_RELAXED,
                                        __HIP_MEMORY_SCOPE_AGENT);
    unsigned short us = (tid & 1) ? (unsigned short)(pv >> 16)
                                  : (unsigned short)(pv & 0xffffu);
    pcur = __builtin_bit_cast(_Float16, us);
  }
  __syncthreads();

  int p = 0;
  for (int t = 0; t < 512; t++) {
    const f32v4* hs4 = (const f32v4*)hbuf[p];
    // watermark refresh (relaxed; consumed late this iteration)
    unsigned int fwnew = fw;
    if (stage != 0)
      fwnew = __hip_atomic_load(inflag, __ATOMIC_RELAXED, __HIP_MEMORY_SCOPE_AGENT);
    // B: early x(t+1) fetch if last iteration's watermark already covers it
    int xv_ok = 0;
    if (stage == 1 && t < 511 && fw >= (unsigned)(t + 2)) {
      asm volatile("" ::: "memory");
      if (tid < 128)
        xv = __hip_atomic_load(in0b + (((size_t)(t + 1)) << 7) + tid,
                               __ATOMIC_RELAXED, __HIP_MEMORY_SCOPE_AGENT);
      xv_ok = 1;
    }
    // streamed W group: issue early, consume last
    f32x4 s0 = q7[0 << 6], s1 = q7[1 << 6], s2 = q7[2 << 6], s3 = q7[3 << 6];
    f32x4 s4 = q7[4 << 6], s5 = q7[5 << 6], s6 = q7[6 << 6], s7 = q7[7 << 6];
    float acc0 = 0.f, acc1 = 0.f, acc2 = 0.f, acc3 = 0.f;
    float acc4 = 0.f, acc5 = 0.f, acc6 = 0.f, acc7 = 0.f;
    DOTG(0) DOTG(1) DOTG(2) DOTG(3) DOTG(4)
    DOTL(0) DOTL(1)
    {
      f32v4 hq = hs4[w8 + 7];
      DOTS(0) DOTS(1) DOTS(2) DOTS(3) DOTS(4) DOTS(5) DOTS(6) DOTS(7)
    }
    float* ps = &psum[w][l];
    ps[0] = acc0;   ps[64] = acc1;  ps[128] = acc2; ps[192] = acc3;
    ps[256] = acc4; ps[320] = acc5; ps[384] = acc6; ps[448] = acc7;
    __syncthreads();  // [A] psum complete
    float sum = psum[0][tid] + psum[1][tid] + psum[2][tid] + psum[3][tid] +
                psum[4][tid] + psum[5][tid] + psum[6][tid] + psum[7][tid];

    if (stage == 0) {
      float s = (float)pcur + sum;
      if (t < 511) pcur = preb[(t + 1) * 512 + tid];
      float z = __expf(2.f * s);
      float hn = fmaf(-2.f, __builtin_amdgcn_rcpf(z + 1.f), 1.f);
      float hn2 = __shfl_down(hn, 1);
      if (!(tid & 1)) {
        __half2 pr = __halves2half2(__float2half(hn), __float2half(hn2));
        __hip_atomic_store(out0b + (((size_t)t) << 8) + (tid >> 1),
                           __builtin_bit_cast(unsigned int, pr),
                           __ATOMIC_RELAXED, __HIP_MEMORY_SCOPE_AGENT);
      }
      hbuf[p ^ 1][tid] = __float2half(hn);
    } else if (stage == 1) {
      float s = bias + sum;
      float s2 = __shfl_down(s, 1);
      if (!(tid & 1)) {
        __half2 pr = __halves2half2(__float2half(s), __float2half(s2));
        __hip_atomic_store(io1b + (((size_t)(t & RING_MASK)) << 8) + (tid >> 1),
                           __builtin_bit_cast(unsigned int, pr),
                           __ATOMIC_RELAXED, __HIP_MEMORY_SCOPE_AGENT);
      }
      if (t < 511) {
        if (!xv_ok) {
          unsigned int need = (unsigned)(t + 2);
          unsigned int fx = (fwnew > fw) ? fwnew : fw;
          if (fx < need) fx = spin_until(inflag, need);
          fw = fx;
          asm volatile("" ::: "memory");
          if (tid < 128)
            xv = __hip_atomic_load(in0b + (((size_t)(t + 1)) << 7) + tid,
                                   __ATOMIC_RELAXED, __HIP_MEMORY_SCOPE_AGENT);
        }
        if (tid < 128) ((unsigned long long*)hbuf[p ^ 1])[tid] = xv;
      }
    } else {
      float s = (float)pcur + sum;
      float z = __expf(2.f * s);
      float hn = fmaf(-2.f, __builtin_amdgcn_rcpf(z + 1.f), 1.f);
      ob32[t * 512 + tid] = hn;
      hbuf[p ^ 1][tid] = __float2half(hn);
      if (t < 511) {
        unsigned int need = (unsigned)(t + 2);
        unsigned int fx = (fwnew > fw) ? fwnew : fw;
        if (fx < need) fx = spin_until(inflag, need);
        fw = fx;
        asm volatile("" ::: "memory");
        unsigned int pv = __hip_atomic_load(
            io1b + (((size_t)((t + 1) & RING_MASK)) << 8) + (tid >> 1),
            __ATOMIC_RELAXED, __HIP_MEMORY_SCOPE_AGENT);
        unsigned short us = (tid & 1) ? (unsigned short)(pv >> 16)
                                      : (unsigned short)(pv & 0xffffu);
        pcur = __builtin_bit_cast(_Float16, us);
      }
    }
    if (stage != 0) fw = (fwnew > fw) ? fwnew : fw;
    p ^= 1;
    __syncthreads();  // [B] hbuf/psum reuse safe; stores drained (vmcnt 0)
    if (stage != 2 && tid == 0)
      __hip_atomic_store(outflag, (unsigned)(t + 1), __ATOMIC_RELEASE,
                         __HIP_MEMORY_SCOPE_AGENT);
  }
}

extern "C" void kernel_launch(void* const* d_in, const int* in_sizes, int n_in,
                              void* d_out, int out_size, void* d_ws, size_t ws_size,
                              hipStream_t stream) {
  const float* x     = (const float*)d_in[0];
  const float* fp    = (const float*)d_in[1];
  const float* fc0_w = (const float*)d_in[2];
  const float* fc0_b = (const float*)d_in[3];
  const float* fc1_w = (const float*)d_in[4];
  const float* fc1_b = (const float*)d_in[5];
  const float* fc2_w = (const float*)d_in[6];
  const float* fc2_b = (const float*)d_in[7];
  const float* fc3_w = (const float*)d_in[8];
  const float* fc3_b = (const float*)d_in[9];
  const float* w_ih0 = (const float*)d_in[10];
  const float* w_hh0 = (const float*)d_in[11];
  const float* b_ih0 = (const float*)d_in[12];
  const float* b_hh0 = (const float*)d_in[13];
  const float* w_ih1 = (const float*)d_in[14];
  const float* w_hh1 = (const float*)d_in[15];
  const float* b_ih1 = (const float*)d_in[16];
  const float* b_hh1 = (const float*)d_in[17];
  float* out = (float*)d_out;
  float* ws  = (float*)d_ws;

  // ws layout (float offsets). Total ~73.8 MB (unchanged).
  _Float16* preH = (_Float16*)ws;                    // [32768][512] fp16
  float* U = ws + 8388608;
  _Float16* h16 = (_Float16*)U;                      // RNN: inbox0 [64][512][512]
  _Float16* t0  = (_Float16*)U;                      // FC phase: [8192][1024]
  float* R2 = U + 4194304;
  _Float16* t1  = (_Float16*)R2;                     // [8192][1024]
  _Float16* zc  = (_Float16*)R2;                     // [8192][256]
  _Float16* f3  = (_Float16*)(R2 + 1048576);         // [8192][128]
  float* wbase = ws + 16777216;
  float4*   QW0   = (float4*)wbase;
  float4*   QW1   = (float4*)(wbase + 131072);
  _Float16* fc0h  = (_Float16*)(wbase + 262144);
  _Float16* fc1h  = (_Float16*)(wbase + 393216);
  _Float16* fc2h  = (_Float16*)(wbase + 917504);
  _Float16* fc3h  = (_Float16*)(wbase + 1441792);
  _Float16* wih0h = (_Float16*)(wbase + 1507328);
  float4*   QWB   = (float4*)(wbase + 1540096);      // packed w_ih1
  // RNN-phase-only aliases of FC-dead regions:
  _Float16* inbox1 = (_Float16*)(wbase + 393216);    // over fc1h/fc2h: 64x64x512 fp16
  unsigned int* flagsBase = (unsigned int*)fc0h;     // 128 u32

  pack_whh_fp16<<<128, 256, 0, stream>>>(w_hh0, QW0);
  pack_whh_fp16<<<128, 256, 0, stream>>>(w_hh1, QW1);
  pack_whh_fp16<<<128, 256, 0, stream>>>(w_ih1, QWB);
  cvt_w16<<<1024, 256, 0, stream>>>(fc0_w, fc0h, 1024, 200, 256);
  cvt_w16<<<4096, 256, 0, stream>>>(fc1_w, fc1h, 1024, 1024, 1024);
  cvt_w16<<<4096, 256, 0, stream>>>(fc2_w, fc2h, 1024, 1024, 1024);
  cvt_w16<<<512, 256, 0, stream>>>(fc3_w, fc3h, 128, 1024, 1024);
  cvt_w16<<<256, 256, 0, stream>>>(w_ih0, wih0h, 512, 128, 128);

  const int CH = 8192;  // 32768 rows in 4 chunks
  for (int c = 0; c < 4; c++) {
    size_t row0 = (size_t)c * CH;
    fuzzy16<<<CH, 256, 0, stream>>>(x + row0 * 50, fp, zc, CH);
    gemm16<<<dim3(8, 64), 256, 0, stream>>>(zc, fc0h, fc0_b, nullptr, t0, CH, 1024, 256);
    gemm16<<<dim3(8, 64), 256, 0, stream>>>(t0, fc1h, fc1_b, nullptr, t1, CH, 1024, 1024);
    gemm16<<<dim3(8, 64), 256, 0, stream>>>(t1, fc2h, fc2_b, nullptr, t0, CH, 1024, 1024);
    gemm16<<<dim3(1, 64), 256, 0, stream>>>(t0, fc3h, fc3_b, nullptr, f3, CH, 128, 1024);
    gemm16<<<dim3(4, 64), 256, 0, stream>>>(f3, wih0h, b_ih0, b_hh0,
                                            preH + row0 * 512, CH, 512, 128);
  }

  // FC done -> fc0h/fc1h/fc2h dead. Zero flags, run the 3-stage pipeline.
  hipMemsetAsync((void*)flagsBase, 0, 128 * sizeof(unsigned int), stream);
  rnn_pipe3_k<<<192, 512, 0, stream>>>(
      preH, (const f32v4*)QW0, (const f32v4*)QWB, (const f32v4*)QW1,
      b_ih1, b_hh1, h16, inbox1, out, flagsBase);
}

// Round 12
// 2174.111 us; speedup vs baseline: 1.9912x; 1.6427x over previous
//
#include <hip/hip_runtime.h>
#include <hip/hip_fp16.h>
#include <cstddef>

// FDRNN: fuzzy -> FC(200->1024->1024->1024->128) -> 2-layer tanh RNN (H=512)
// B=64, S=512 -> 32768 rows.
//
// R12 (resubmit; round 11 lost to broker timeout): R11 pipeline was correct
// but 3.9x slow. Two poisons: (1) RELEASE flag stores at agent scope emit
// buffer_wbl2 (full L2 writeback) every step; (2) the 5/2/1 core spills ~36
// regs -> 24 blocks/XCD x ~100KB private scratch thrashes the 4MB XCD L2
// (FETCH 18.7->63MB). R12: RELAXED flags (syncthreads' vmcnt drain already
// orders data-before-flag, R6-proven), core re-balanced 1 pinned / 2 LDS /
// 5 streamed (peak ~100 regs, ZERO spill; streamed W is shared clean
// L2-resident QW), padded flags (128B), ring backpressure. Stage step
// ~3500-4000 cyc -> pipeline wall ~850us replacing serial 776+55+776.

typedef _Float16 half8 __attribute__((ext_vector_type(8)));
typedef float f32x4 __attribute__((ext_vector_type(4)));
typedef float f32v4 __attribute__((ext_vector_type(4)));
typedef _Float16 v2h __attribute__((ext_vector_type(2)));

__device__ __forceinline__ void gld_lds16(const void* g, void* lds) {
  __builtin_amdgcn_global_load_lds(
      (const __attribute__((address_space(1))) unsigned int*)g,
      (__attribute__((address_space(3))) unsigned int*)lds, 16, 0, 0);
}

// ---------------- fuzzy (fp16 out, K padded 200->256) ----------------
__global__ void fuzzy16(const float* __restrict__ x, const float* __restrict__ fp,
                        _Float16* __restrict__ z, int nrows) {
  int idx = blockIdx.x * blockDim.x + threadIdx.x;
  if (idx >= nrows * 256) return;
  int r = idx >> 8;
  int f = idx & 255;
  float v = 0.f;
  if (f < 200) {
    int i = f % 50;
    float xv = x[r * 50 + i];
    float mu = fp[2 * f];
    float sg = fp[2 * f + 1];
    float d = xv - mu;
    v = expf(-(d * d) / sg);
  }
  z[idx] = (_Float16)v;
}

// ---------------- weight fp32 -> fp16 (with optional K zero-pad) -------------
__global__ void cvt_w16(const float* __restrict__ W, _Float16* __restrict__ O,
                        int rows, int kin, int kpad) {
  int idx = blockIdx.x * blockDim.x + threadIdx.x;
  if (idx >= rows * kpad) return;
  int r = idx / kpad;
  int k = idx - r * kpad;
  O[idx] = (k < kin) ? (_Float16)W[(size_t)r * kin + k] : (_Float16)0.f;
}

// ---------------- MFMA fp16 GEMM: C16[M][N] = A16[M][K] @ W16[N][K]^T + b ----
__global__ __launch_bounds__(256) void gemm16(
    const _Float16* __restrict__ A, const _Float16* __restrict__ W,
    const float* __restrict__ b1, const float* __restrict__ b2,
    _Float16* __restrict__ C, int M, int N, int K) {
  __shared__ _Float16 As[128 * 32];
  __shared__ _Float16 Bs[128 * 32];
  const int tid = threadIdx.x;
  const int bm = blockIdx.y * 128;
  const int bn = blockIdx.x * 128;
  const int lane = tid & 63;
  const int wv = tid >> 6;
  const int wm = (wv >> 1) * 64;
  const int wn = (wv & 1) * 64;
  const int frow = lane & 15;
  const int fk = (lane >> 4) * 8;

  const int srow = tid >> 2;
  const int scol = (tid & 3) * 16;  // bytes
  const char* gA = (const char*)(A + (size_t)(bm + srow) * K) + scol;
  const char* gB = (const char*)(W + (size_t)(bn + srow) * K) + scol;
  const size_t rowstep = (size_t)64 * K * 2;
  char* lA = (char*)As + tid * 16;
  char* lB = (char*)Bs + tid * 16;

  f32x4 acc[4][4] = {};

  for (int k0 = 0; k0 < K; k0 += 32) {
    gld_lds16(gA, lA);
    gld_lds16(gA + rowstep, lA + 4096);
    gld_lds16(gB, lB);
    gld_lds16(gB + rowstep, lB + 4096);
    gA += 64;
    gB += 64;
    __syncthreads();
    half8 af[4], bf[4];
#pragma unroll
    for (int i = 0; i < 4; i++) {
      af[i] = *(const half8*)(As + (wm + i * 16 + frow) * 32 + fk);
      bf[i] = *(const half8*)(Bs + (wn + i * 16 + frow) * 32 + fk);
    }
#pragma unroll
    for (int i = 0; i < 4; i++)
#pragma unroll
      for (int j = 0; j < 4; j++)
        acc[i][j] = __builtin_amdgcn_mfma_f32_16x16x32_f16(af[i], bf[j], acc[i][j], 0, 0, 0);
    __syncthreads();
  }

  float bias[4];
#pragma unroll
  for (int j = 0; j < 4; j++) {
    int col = bn + wn + j * 16 + frow;
    bias[j] = b1[col] + (b2 ? b2[col] : 0.f);
  }
  const int r0 = (lane >> 4) * 4;
#pragma unroll
  for (int i = 0; i < 4; i++) {
#pragma unroll
    for (int r = 0; r < 4; r++) {
      int row = bm + wm + i * 16 + r0 + r;
      _Float16* Cp = C + (size_t)row * N + bn + wn + frow;
#pragma unroll
      for (int j = 0; j < 4; j++)
        Cp[j * 16] = (_Float16)(acc[i][j][r] + bias[j]);
    }
  }
}

// ---------------- RNN weight pack (fp32 -> fp16, 16B groups) ----------------
// QW[j4*512 + o] = 8 fp16 = w[o][8*j4 .. 8*j4+7]
__global__ void pack_whh_fp16(const float* __restrict__ W, float4* __restrict__ QW) {
  int idx = blockIdx.x * blockDim.x + threadIdx.x;
  if (idx >= 32768) return;
  int j4 = idx >> 9;
  int o = idx & 511;
  const float* src = W + (size_t)o * 512 + j4 * 8;
  __align__(16) __half2 p[4];
#pragma unroll
  for (int k = 0; k < 4; k++)
    p[k] = __halves2half2(__float2half(src[2 * k]), __float2half(src[2 * k + 1]));
  QW[idx] = *(const float4*)p;
}

__device__ __forceinline__ float dot2acc(float wbits, float hbits, float acc) {
#if __has_builtin(__builtin_amdgcn_fdot2)
  return __builtin_amdgcn_fdot2(__builtin_bit_cast(v2h, wbits),
                                __builtin_bit_cast(v2h, hbits), acc, false);
#else
  float2 wf = __half22float2(__builtin_bit_cast(__half2, wbits));
  float2 hf = __half22float2(__builtin_bit_cast(__half2, hbits));
  return fmaf(wf.x, hf.x, fmaf(wf.y, hf.y, acc));
#endif
}

__device__ __forceinline__ unsigned int spin_until(unsigned int* f, unsigned int need) {
  unsigned int v = __hip_atomic_load(f, __ATOMIC_RELAXED, __HIP_MEMORY_SCOPE_AGENT);
  while (v < need) {
    __builtin_amdgcn_s_sleep(8);
    v = __hip_atomic_load(f, __ATOMIC_RELAXED, __HIP_MEMORY_SCOPE_AGENT);
  }
  return v;
}

// Matvec core, zero-spill balance: per thread 8 o-rows (o=l+64k) x 8 j-groups.
// Group 0 pinned VGPR (32 regs), groups 5,6 LDS, groups 1,2,3,4,7 streamed
// (clean shared L2 reads of QW; no scratch). Peak regs ~100 < 128 budget.
#define DECLP(k) \
  f32x4 wp##k = qb[(k) << 6]; asm volatile("" : "+v"(wp##k));

#define DOTP(k)                               \
  acc##k = dot2acc(wp##k.x, hq.x, acc##k);    \
  acc##k = dot2acc(wp##k.y, hq.y, acc##k);    \
  acc##k = dot2acc(wp##k.z, hq.z, acc##k);    \
  acc##k = dot2acc(wp##k.w, hq.w, acc##k);

#define DOTPG()                               \
  {                                           \
    f32v4 hq = hs4[w8];                       \
    DOTP(0) DOTP(1) DOTP(2) DOTP(3)           \
    DOTP(4) DOTP(5) DOTP(6) DOTP(7)           \
  }

#define DOTLK(gp, k)                                \
  {                                                 \
    f32v4 q = wl[((gp) << 9) + ((k) << 6)];         \
    acc##k = dot2acc(q.x, hq.x, acc##k);            \
    acc##k = dot2acc(q.y, hq.y, acc##k);            \
    acc##k = dot2acc(q.z, hq.z, acc##k);            \
    acc##k = dot2acc(q.w, hq.w, acc##k);            \
  }

#define DOTL(gp)                                    \
  {                                                 \
    f32v4 hq = hs4[w8 + 5 + (gp)];                  \
    DOTLK(gp, 0) DOTLK(gp, 1) DOTLK(gp, 2)          \
    DOTLK(gp, 3) DOTLK(gp, 4) DOTLK(gp, 5)          \
    DOTLK(gp, 6) DOTLK(gp, 7)                       \
  }

#define SLOADG(g)                                   \
  {                                                 \
    const f32v4* qg = qb + ((size_t)(g) << 9);      \
    s0 = qg[0];   s1 = qg[64];  s2 = qg[128];       \
    s3 = qg[192]; s4 = qg[256]; s5 = qg[320];       \
    s6 = qg[384]; s7 = qg[448];                     \
  }

#define DOTS1(k)                                    \
  acc##k = dot2acc(s##k.x, hq.x, acc##k);           \
  acc##k = dot2acc(s##k.y, hq.y, acc##k);           \
  acc##k = dot2acc(s##k.z, hq.z, acc##k);           \
  acc##k = dot2acc(s##k.w, hq.w, acc##k);

#define DOTSG(g)                                    \
  {                                                 \
    f32v4 hq = hs4[w8 + (g)];                       \
    DOTS1(0) DOTS1(1) DOTS1(2) DOTS1(3)             \
    DOTS1(4) DOTS1(5) DOTS1(6) DOTS1(7)             \
  }

#define RING_MASK 63  // inbox1 ring depth 64 steps
#define FPAD 32       // flags padded to 128B lines

// ---------------- 3-stage pipelined RNN ----------------
// grid 192: bid>>6 = stage (0=A w_hh0, 1=B w_ih1, 2=C w_hh1), b = bid&63.
// A: local h0 recurrence; publish h0_t -> inbox0 + flag0 (RELAXED after the
//    barrier's vmcnt drain -- data already at L3 when flag lands).
// B: x = inbox0[t]; publish pre1_t -> inbox1 ring + flag1; backpressure on
//    C's progress every 16 steps.
// C: local h1 recurrence on inbox1[t]; out fp32; publish progress.
__global__ __attribute__((amdgpu_flat_work_group_size(512, 512),
                          amdgpu_waves_per_eu(2, 2)))
void rnn_pipe3_k(
    const _Float16* __restrict__ pre0,  // [64][512][512] stage-A pre (biases folded)
    const f32v4* __restrict__ QWA,      // packed w_hh0
    const f32v4* __restrict__ QWB,      // packed w_ih1
    const f32v4* __restrict__ QWC,      // packed w_hh1
    const float* __restrict__ bih1, const float* __restrict__ bhh1,
    _Float16* __restrict__ inbox0,      // [64][512][512] h0 (A->B)
    _Float16* __restrict__ inbox1,      // [64][64][512] pre1 ring (B->C)
    float* __restrict__ out32,          // [64][512][512] final
    unsigned int* __restrict__ flags) { // padded: [b]=A, [64+b]=B, [128+b]=C prog
  const int bid = blockIdx.x;
  const int stage = bid >> 6;
  const int b = bid & 63;
  const int tid = threadIdx.x;
  const int w = tid >> 6;
  const int l = tid & 63;
  const int w8 = w << 3;

  __shared__ f32v4 wlds[16][512];                // 128 KB
  __shared__ float psum[8][512];                 // 16 KB
  __shared__ __align__(16) __half hbuf[2][512];  // 2 KB

  const f32v4* QW = (stage == 0) ? QWA : (stage == 1) ? QWB : QWC;
  const f32v4* qb = QW + ((size_t)(w8) << 9) + l;
  DECLP(0) DECLP(1) DECLP(2) DECLP(3) DECLP(4) DECLP(5) DECLP(6) DECLP(7)

  f32v4* wl = &wlds[w << 1][l];
#pragma unroll
  for (int gp = 0; gp < 2; gp++)
#pragma unroll
    for (int k = 0; k < 8; k++)
      wl[(gp << 9) + (k << 6)] = qb[((5 + gp) << 9) + (k << 6)];

  unsigned int* inflag  = (stage == 1) ? (flags + b * FPAD)
                                       : (flags + (64 + b) * FPAD);
  unsigned int* outflag = (stage == 0) ? (flags + b * FPAD)
                        : (stage == 1) ? (flags + (64 + b) * FPAD)
                                       : (flags + (128 + b) * FPAD);
  unsigned int* cprog   = flags + (128 + b) * FPAD;
  unsigned long long* in0b = (unsigned long long*)(inbox0 + ((size_t)b << 18));
  unsigned int* out0b = (unsigned int*)(inbox0 + ((size_t)b << 18));
  unsigned int* io1b = (unsigned int*)(inbox1 + ((size_t)b << 15));
  const _Float16* preb = pre0 + ((size_t)b << 18);
  float* ob32 = out32 + ((size_t)b << 18);

  unsigned int fw = 0;
  float bias = 0.f;
  _Float16 pcur = (_Float16)0.f;
  unsigned long long xv = 0;

  if (stage == 0) {
    pcur = preb[tid];
    hbuf[0][tid] = __float2half(0.f);
  } else if (stage == 1) {
    bias = bih1[tid] + bhh1[tid];
    fw = spin_until(inflag, 1u);
    asm volatile("" ::: "memory");
    if (tid < 128) {
      unsigned long long v = __hip_atomic_load(in0b + tid, __ATOMIC_RELAXED,
                                               __HIP_MEMORY_SCOPE_AGENT);
      ((unsigned long long*)hbuf[0])[tid] = v;
    }
  } else {
    hbuf[0][tid] = __float2half(0.f);
    fw = spin_until(inflag, 1u);
    asm volatile("" ::: "memory");
    unsigned int pv = __hip_atomic_load(io1b + (tid >> 1), __ATOMIC_RELAXED,
                                        __HIP_MEMORY_SCOPE_AGENT);
    unsigned short us = (tid & 1) ? (unsigned short)(pv >> 16)
                                  : (unsigned short)(pv & 0xffffu);
    pcur = __builtin_bit_cast(_Float16, us);
  }
  __syncthreads();

  int p = 0;
  for (int t = 0; t < 512; t++) {
    const f32v4* hs4 = (const f32v4*)hbuf[p];
    // B backpressure: never lead C by more than ~48 ring slots (depth 64).
    if (stage == 1 && (t & 15) == 0 && t >= 56) {
      unsigned int cp = __hip_atomic_load(cprog, __ATOMIC_RELAXED,
                                          __HIP_MEMORY_SCOPE_AGENT);
      if (cp + 48 <= (unsigned)t) spin_until(cprog, (unsigned)t - 48);
    }
    // watermark refresh (relaxed; folded late)
    unsigned int fwnew = fw;
    if (stage != 0)
      fwnew = __hip_atomic_load(inflag, __ATOMIC_RELAXED, __HIP_MEMORY_SCOPE_AGENT);
    // B: early x(t+1) fetch when the cached watermark already covers it
    int xv_ok = 0;
    if (stage == 1 && t < 511 && fw >= (unsigned)(t + 2)) {
      asm volatile("" ::: "memory");
      if (tid < 128)
        xv = __hip_atomic_load(in0b + (((size_t)(t + 1)) << 7) + tid,
                               __ATOMIC_RELAXED, __HIP_MEMORY_SCOPE_AGENT);
      xv_ok = 1;
    }
    float acc0 = 0.f, acc1 = 0.f, acc2 = 0.f, acc3 = 0.f;
    float acc4 = 0.f, acc5 = 0.f, acc6 = 0.f, acc7 = 0.f;
    f32x4 s0, s1, s2, s3, s4, s5, s6, s7;
    SLOADG(1)
    DOTPG()       // pinned group 0
    DOTSG(1)
    SLOADG(2)
    DOTL(0)       // LDS group 5
    DOTSG(2)
    SLOADG(3)
    DOTL(1)       // LDS group 6
    DOTSG(3)
    SLOADG(4)
    DOTSG(4)
    SLOADG(7)
    DOTSG(7)
    float* ps = &psum[w][l];
    ps[0] = acc0;   ps[64] = acc1;  ps[128] = acc2; ps[192] = acc3;
    ps[256] = acc4; ps[320] = acc5; ps[384] = acc6; ps[448] = acc7;
    __syncthreads();  // [A] psum complete
    float sum = psum[0][tid] + psum[1][tid] + psum[2][tid] + psum[3][tid] +
                psum[4][tid] + psum[5][tid] + psum[6][tid] + psum[7][tid];

    if (stage == 0) {
      float s = (float)pcur + sum;
      if (t < 511) pcur = preb[(t + 1) * 512 + tid];
      float z = __expf(2.f * s);
      float hn = fmaf(-2.f, __builtin_amdgcn_rcpf(z + 1.f), 1.f);
      float hn2 = __shfl_down(hn, 1);
      if (!(tid & 1)) {
        __half2 pr = __halves2half2(__float2half(hn), __float2half(hn2));
        __hip_atomic_store(out0b + (((size_t)t) << 8) + (tid >> 1),
                           __builtin_bit_cast(unsigned int, pr),
                           __ATOMIC_RELAXED, __HIP_MEMORY_SCOPE_AGENT);
      }
      hbuf[p ^ 1][tid] = __float2half(hn);
    } else if (stage == 1) {
      float s = bias + sum;
      float s2 = __shfl_down(s, 1);
      if (!(tid & 1)) {
        __half2 pr = __halves2half2(__float2half(s), __float2half(s2));
        __hip_atomic_store(io1b + (((size_t)(t & RING_MASK)) << 8) + (tid >> 1),
                           __builtin_bit_cast(unsigned int, pr),
                           __ATOMIC_RELAXED, __HIP_MEMORY_SCOPE_AGENT);
      }
      if (t < 511) {
        if (!xv_ok) {
          unsigned int need = (unsigned)(t + 2);
          unsigned int fx = (fwnew > fw) ? fwnew : fw;
          if (fx < need) fx = spin_until(inflag, need);
          fw = fx;
          asm volatile("" ::: "memory");
          if (tid < 128)
            xv = __hip_atomic_load(in0b + (((size_t)(t + 1)) << 7) + tid,
                                   __ATOMIC_RELAXED, __HIP_MEMORY_SCOPE_AGENT);
        }
        if (tid < 128) ((unsigned long long*)hbuf[p ^ 1])[tid] = xv;
      }
    } else {
      float s = (float)pcur + sum;
      float z = __expf(2.f * s);
      float hn = fmaf(-2.f, __builtin_amdgcn_rcpf(z + 1.f), 1.f);
      ob32[t * 512 + tid] = hn;
      hbuf[p ^ 1][tid] = __float2half(hn);
      if (t < 511) {
        unsigned int need = (unsigned)(t + 2);
        unsigned int fx = (fwnew > fw) ? fwnew : fw;
        if (fx < need) fx = spin_until(inflag, need);
        fw = fx;
        asm volatile("" ::: "memory");
        unsigned int pv = __hip_atomic_load(
            io1b + (((size_t)((t + 1) & RING_MASK)) << 8) + (tid >> 1),
            __ATOMIC_RELAXED, __HIP_MEMORY_SCOPE_AGENT);
        unsigned short us = (tid & 1) ? (unsigned short)(pv >> 16)
                                      : (unsigned short)(pv & 0xffffu);
        pcur = __builtin_bit_cast(_Float16, us);
      }
    }
    if (stage != 0) fw = (fwnew > fw) ? fwnew : fw;
    p ^= 1;
    __syncthreads();  // [B] drains vmcnt(0): all sc1 data stores at L3
    if (tid == 0)     // RELAXED flag after drain -- ordered, no buffer_wbl2
      __hip_atomic_store(outflag, (unsigned)(t + 1), __ATOMIC_RELAXED,
                         __HIP_MEMORY_SCOPE_AGENT);
  }
}

extern "C" void kernel_launch(void* const* d_in, const int* in_sizes, int n_in,
                              void* d_out, int out_size, void* d_ws, size_t ws_size,
                              hipStream_t stream) {
  const float* x     = (const float*)d_in[0];
  const float* fp    = (const float*)d_in[1];
  const float* fc0_w = (const float*)d_in[2];
  const float* fc0_b = (const float*)d_in[3];
  const float* fc1_w = (const float*)d_in[4];
  const float* fc1_b = (const float*)d_in[5];
  const float* fc2_w = (const float*)d_in[6];
  const float* fc2_b = (const float*)d_in[7];
  const float* fc3_w = (const float*)d_in[8];
  const float* fc3_b = (const float*)d_in[9];
  const float* w_ih0 = (const float*)d_in[10];
  const float* w_hh0 = (const float*)d_in[11];
  const float* b_ih0 = (const float*)d_in[12];
  const float* b_hh0 = (const float*)d_in[13];
  const float* w_ih1 = (const float*)d_in[14];
  const float* w_hh1 = (const float*)d_in[15];
  const float* b_ih1 = (const float*)d_in[16];
  const float* b_hh1 = (const float*)d_in[17];
  float* out = (float*)d_out;
  float* ws  = (float*)d_ws;

  // ws layout (float offsets). Total ~73.8 MB (unchanged).
  _Float16* preH = (_Float16*)ws;                    // [32768][512] fp16
  float* U = ws + 8388608;
  _Float16* h16 = (_Float16*)U;                      // RNN: inbox0 [64][512][512]
  _Float16* t0  = (_Float16*)U;                      // FC phase: [8192][1024]
  float* R2 = U + 4194304;
  _Float16* t1  = (_Float16*)R2;                     // [8192][1024]
  _Float16* zc  = (_Float16*)R2;                     // [8192][256]
  _Float16* f3  = (_Float16*)(R2 + 1048576);         // [8192][128]
  float* wbase = ws + 16777216;
  float4*   QW0   = (float4*)wbase;
  float4*   QW1   = (float4*)(wbase + 131072);
  _Float16* fc0h  = (_Float16*)(wbase + 262144);
  _Float16* fc1h  = (_Float16*)(wbase + 393216);
  _Float16* fc2h  = (_Float16*)(wbase + 917504);
  _Float16* fc3h  = (_Float16*)(wbase + 1441792);
  _Float16* wih0h = (_Float16*)(wbase + 1507328);
  float4*   QWB   = (float4*)(wbase + 1540096);      // packed w_ih1
  // RNN-phase-only aliases of FC-dead regions:
  _Float16* inbox1 = (_Float16*)(wbase + 393216);    // over fc1h: 64x64x512 fp16
  unsigned int* flagsBase = (unsigned int*)fc0h;     // 192 x 32 u32 = 24 KB

  pack_whh_fp16<<<128, 256, 0, stream>>>(w_hh0, QW0);
  pack_whh_fp16<<<128, 256, 0, stream>>>(w_hh1, QW1);
  pack_whh_fp16<<<128, 256, 0, stream>>>(w_ih1, QWB);
  cvt_w16<<<1024, 256, 0, stream>>>(fc0_w, fc0h, 1024, 200, 256);
  cvt_w16<<<4096, 256, 0, stream>>>(fc1_w, fc1h, 1024, 1024, 1024);
  cvt_w16<<<4096, 256, 0, stream>>>(fc2_w, fc2h, 1024, 1024, 1024);
  cvt_w16<<<512, 256, 0, stream>>>(fc3_w, fc3h, 128, 1024, 1024);
  cvt_w16<<<256, 256, 0, stream>>>(w_ih0, wih0h, 512, 128, 128);

  const int CH = 8192;  // 32768 rows in 4 chunks
  for (int c = 0; c < 4; c++) {
    size_t row0 = (size_t)c * CH;
    fuzzy16<<<CH, 256, 0, stream>>>(x + row0 * 50, fp, zc, CH);
    gemm16<<<dim3(8, 64), 256, 0, stream>>>(zc, fc0h, fc0_b, nullptr, t0, CH, 1024, 256);
    gemm16<<<dim3(8, 64), 256, 0, stream>>>(t0, fc1h, fc1_b, nullptr, t1, CH, 1024, 1024);
    gemm16<<<dim3(8, 64), 256, 0, stream>>>(t1, fc2h, fc2_b, nullptr, t0, CH, 1024, 1024);
    gemm16<<<dim3(1, 64), 256, 0, stream>>>(t0, fc3h, fc3_b, nullptr, f3, CH, 128, 1024);
    gemm16<<<dim3(4, 64), 256, 0, stream>>>(f3, wih0h, b_ih0, b_hh0,
                                            preH + row0 * 512, CH, 512, 128);
  }

  // FC done -> fc0h/fc1h dead. Zero padded flags, run the 3-stage pipeline.
  hipMemsetAsync((void*)flagsBase, 0, 192 * 32 * sizeof(unsigned int), stream);
  rnn_pipe3_k<<<192, 512, 0, stream>>>(
      preH, (const f32v4*)QW0, (const f32v4*)QWB, (const f32v4*)QW1,
      b_ih1, b_hh1, h16, inbox1, out, flagsBase);
}